// Round 17
// baseline (355.692 us; speedup 1.0000x reference)
//
#include <hip/hip_runtime.h>
#include <hip/hip_bf16.h>

// ---------------- common types/helpers ----------------
typedef __bf16 bf16x8 __attribute__((ext_vector_type(8)));
typedef float  f32x4  __attribute__((ext_vector_type(4)));
typedef unsigned short u16x8 __attribute__((ext_vector_type(8)));
typedef unsigned short u16x4 __attribute__((ext_vector_type(4)));
typedef unsigned u32x4 __attribute__((ext_vector_type(4)));
typedef unsigned long long u64x2 __attribute__((ext_vector_type(2)));

#define T_TOK   8200      // C*(1+NCHUNK)
#define M_TOK   16400     // B*T
#define QKV_LD  3072
#define DM      1024

#define AS1CU const __attribute__((address_space(1))) unsigned int*
#define AS3U  __attribute__((address_space(3))) unsigned int*
#define GLDS16(g, s) __builtin_amdgcn_global_load_lds((AS1CU)(g), (AS3U)(s), 16, 0, 0)

__device__ __forceinline__ unsigned short f2bf(float f){
  __hip_bfloat16 h = __float2bfloat16(f);          // HW RNE cvt
  return *reinterpret_cast<unsigned short*>(&h);
}
__device__ __forceinline__ float bf2f(unsigned short u){
  union { unsigned u; float f; } x; x.u = ((unsigned)u) << 16;
  return x.f;
}

// ---------------- 1) fused prep: fp32->bf16 convert (blocks 0..2047) + 4x weight transpose (2048..3071) ----------------
__global__ __launch_bounds__(256) void k_prep(const float* __restrict__ x, unsigned short* __restrict__ xb,
                                              const float* __restrict__ Wq, const float* __restrict__ Wk,
                                              const float* __restrict__ Wv, const float* __restrict__ Wo,
                                              unsigned short* __restrict__ wqkvt, unsigned short* __restrict__ wot){
  __shared__ float t[64][65];
  int bid = blockIdx.x, tid = threadIdx.x;
  if (bid < 2048){
    const long n4 = (long)M_TOK * 1024 / 4;
    long i = (long)bid * 256 + tid;
    const long stride = 2048L * 256;
    for (long e = i; e < n4; e += stride){
      float4 v = ((const float4*)x)[e];
      u16x4 o; o[0]=f2bf(v.x); o[1]=f2bf(v.y); o[2]=f2bf(v.z); o[3]=f2bf(v.w);
      ((u16x4*)xb)[e] = o;
    }
    return;
  }
  int bid2 = bid - 2048;
  int z = bid2 & 3; int rest = bid2 >> 2;
  int bx = rest & 15, by = rest >> 4;
  const float* W; unsigned short* Wt;
  if      (z == 0){ W = Wq; Wt = wqkvt; }
  else if (z == 1){ W = Wk; Wt = wqkvt + (size_t)1024*1024; }
  else if (z == 2){ W = Wv; Wt = wqkvt + (size_t)2048*1024; }
  else            { W = Wo; Wt = wot; }
  int tk0 = bx * 64, tn0 = by * 64;
#pragma unroll
  for (int i = 0; i < 4; i++){
    int ch = tid + i*256; int kr = ch >> 4, n4i = (ch & 15) * 4;
    float4 v = *(const float4*)(W + (size_t)(tk0+kr)*1024 + tn0 + n4i);
    t[kr][n4i+0]=v.x; t[kr][n4i+1]=v.y; t[kr][n4i+2]=v.z; t[kr][n4i+3]=v.w;
  }
  __syncthreads();
#pragma unroll
  for (int i = 0; i < 4; i++){
    int ch = tid + i*256; int nr = ch >> 4, k4 = (ch & 15) * 4;
    u16x4 o;
#pragma unroll
    for (int e = 0; e < 4; e++) o[e] = f2bf(t[k4+e][nr]);
    *(u16x4*)(Wt + (size_t)(tn0+nr)*1024 + tk0 + k4) = o;
  }
}

// ---------------- 2) GEMM: minimum 2-phase counted-drain schedule (T3 recipe, m248v2) ----------------
// Double-buffered LDS; next-tile global_load_lds issued BEFORE current tile's
// ds_read+MFMA; ONE __syncthreads() per K-step (its implicit vmcnt(0) drain lands
// after the loads had the whole MFMA phase to complete). n-fast tile order (R7).
__global__ __launch_bounds__(256,2) void k_gemm(const unsigned short* __restrict__ A,
                                                const unsigned short* __restrict__ Bt,
                                                const float* __restrict__ bias,
                                                void* __restrict__ Cout,
                                                int M, int K, int ldc, int bf16out, int gn){
  __shared__ unsigned short As[2][128][64];
  __shared__ unsigned short Bs[2][128][64];
  int tid = threadIdx.x, l = tid & 63, w = tid >> 6;
  int li = l & 15, lh = l >> 4;
  int nwg = gridDim.x;
  int wg = (blockIdx.x & 7) * (nwg >> 3) + (blockIdx.x >> 3);
  int m0 = (wg / gn) * 128, n0 = (wg % gn) * 128;   // n-fast
  int wm = (w & 1) * 64, wn = (w >> 1) * 64;
  int lr = l >> 3, lc = l & 7;
  int lsw = li & 7;

#define STAGE(buf, kt) do{ \
    _Pragma("unroll") \
    for (int i_ = 0; i_ < 4; i_++){ \
      int r_ = w*32 + i_*8 + lr; \
      int colsw_ = (lc ^ (r_ & 7)) * 8; \
      int rga_ = m0 + r_; if (rga_ >= M) rga_ = M - 1; \
      GLDS16(A  + (size_t)rga_     *K + (kt) + colsw_, &As[buf][w*32 + i_*8][0]); \
      GLDS16(Bt + (size_t)(n0 + r_)*K + (kt) + colsw_, &Bs[buf][w*32 + i_*8][0]); \
    } }while(0)

  f32x4 acc[4][4];
#pragma unroll
  for (int a = 0; a < 4; a++)
#pragma unroll
    for (int b = 0; b < 4; b++) acc[a][b] = 0.f;

  // prologue: stage tile 0
  STAGE(0, 0);
  __syncthreads();

  int nt = K >> 6;
  int cur = 0;
  for (int t = 0; t < nt; ++t){
    if (t + 1 < nt) STAGE(cur ^ 1, (t + 1) * 64);   // issue next-tile loads FIRST
#pragma unroll
    for (int ks = 0; ks < 2; ks++){
      bf16x8 af[4], bfr[4];
#pragma unroll
      for (int mt = 0; mt < 4; mt++)
        af[mt] = *(const bf16x8*)&As[cur][wm + mt*16 + li][((ks*4 + lh) ^ lsw) * 8];
#pragma unroll
      for (int nt2 = 0; nt2 < 4; nt2++)
        bfr[nt2] = *(const bf16x8*)&Bs[cur][wn + nt2*16 + li][((ks*4 + lh) ^ lsw) * 8];
      __builtin_amdgcn_s_setprio(1);
#pragma unroll
      for (int mt = 0; mt < 4; mt++)
#pragma unroll
        for (int nt2 = 0; nt2 < 4; nt2++)
          acc[mt][nt2] = __builtin_amdgcn_mfma_f32_16x16x32_bf16(af[mt], bfr[nt2], acc[mt][nt2], 0, 0, 0);
      __builtin_amdgcn_s_setprio(0);
    }
    __syncthreads();       // one barrier per tile: drains next-tile loads (vmcnt 0)
    cur ^= 1;
  }
#undef STAGE

#pragma unroll
  for (int mt = 0; mt < 4; mt++)
#pragma unroll
    for (int nt2 = 0; nt2 < 4; nt2++)
#pragma unroll
      for (int r = 0; r < 4; r++){
        int row = m0 + wm + mt*16 + lh*4 + r;
        int col = n0 + wn + nt2*16 + li;
        if (row < M){
          float v = acc[mt][nt2][r] + (bias ? bias[col] : 0.f);
          if (bf16out) ((unsigned short*)Cout)[(size_t)row*ldc + col] = f2bf(v);
          else         ((float*)Cout)[(size_t)row*ldc + col] = v;
        }
      }
}

// ---------------- 3) attention: global-token blocks FIRST (0..255), local blocks 256..2303 ----------------
// Local path v11 (R16 proven): joint-S + ks-outer PV with vf shared across tr.
__global__ __launch_bounds__(256,3) void k_local(const unsigned short* __restrict__ qkv,
                                                 unsigned short* __restrict__ att){
  __shared__ unsigned short Ks[128][64];      // K tile, granule-swizzled | overlay for global path
  __shared__ unsigned short Vt[64][136];      // V tile transposed [d][j]

  int tid = threadIdx.x;

  if (blockIdx.x < 256){
    // ---- global-token attention (one block per (b,h,c)) ----
    float* sc   = (float*)&Ks[0][0];          // [1032]
    float* red  = sc + 1032;                  // [256]
    float* gq_s = red + 256;                  // [64]
    int gid = blockIdx.x;
    int c = gid & 7, h = (gid >> 3) & 15, b = gid >> 7;
    size_t bT = (size_t)b * T_TOK;
    size_t grow = bT + (size_t)c*1025;
    if (tid < 64) gq_s[tid] = bf2f(qkv[grow*QKV_LD + h*64 + tid]);
    __syncthreads();
    float lmax = -3e38f;
    for (int idx = tid; idx < 1032; idx += 256){
      size_t krow = (idx < 8) ? (bT + (size_t)idx*1025) : (bT + (size_t)c*1025 + 1 + (idx - 8));
      const unsigned short* kp = qkv + krow*QKV_LD + 1024 + h*64;
      float s = 0.f;
#pragma unroll
      for (int d0 = 0; d0 < 64; d0 += 8){
        u16x8 kv = *(const u16x8*)(kp + d0);
#pragma unroll
        for (int e = 0; e < 8; e++) s += gq_s[d0+e] * bf2f(kv[e]);
      }
      s *= 0.125f;
      sc[idx] = s;
      lmax = fmaxf(lmax, s);
    }
    red[tid] = lmax; __syncthreads();
    for (int st = 128; st > 0; st >>= 1){ if (tid < st) red[tid] = fmaxf(red[tid], red[tid+st]); __syncthreads(); }
    float m = red[0]; __syncthreads();
    float lsum = 0.f;
    for (int idx = tid; idx < 1032; idx += 256){
      float p = __expf(sc[idx] - m); sc[idx] = p; lsum += p;
    }
    red[tid] = lsum; __syncthreads();
    for (int st = 128; st > 0; st >>= 1){ if (tid < st) red[tid] += red[tid+st]; __syncthreads(); }
    float denom = red[0]; __syncthreads();
    int d = tid & 63, part = tid >> 6;
    float acc = 0.f;
    for (int idx = part; idx < 1032; idx += 4){
      size_t krow = (idx < 8) ? (bT + (size_t)idx*1025) : (bT + (size_t)c*1025 + 1 + (idx - 8));
      acc += sc[idx] * bf2f(qkv[krow*QKV_LD + 2048 + h*64 + d]);
    }
    red[tid] = acc; __syncthreads();
    if (tid < 64){
      float o = (red[tid] + red[tid+64] + red[tid+128] + red[tid+192]) / denom;
      att[grow*DM + h*64 + tid] = f2bf(o);
    }
    return;
  }

  // ---- local sparse 3-block attention (v11) ----
  int l = tid & 63, w = tid >> 6;
  int li = l & 15, lh = l >> 4;
  int lr = l >> 3, lc = l & 7;
  int lsw = li & 7;
  int wg0 = blockIdx.x - 256;
  int wg = (wg0 & 7) * 256 + (wg0 >> 3);    // XCD-chunked over 2048
  int blk = wg & 7, c = (wg >> 3) & 7, h = (wg >> 6) & 15, b = wg >> 10;
  size_t bT = (size_t)b * T_TOK;
  int tokq0 = c*1025 + 1 + blk*128;

  bf16x8 aq[2][2];
#pragma unroll
  for (int tr = 0; tr < 2; tr++)
#pragma unroll
    for (int ks = 0; ks < 2; ks++)
      aq[tr][ks] = *(const bf16x8*)(qkv + (bT + tokq0 + w*32 + tr*16 + li)*QKV_LD + h*64 + ks*32 + lh*8);

  float psum[2] = {0.f, 0.f};
  f32x4 oacc[2][4];
#pragma unroll
  for (int tr = 0; tr < 2; tr++)
#pragma unroll
    for (int ct = 0; ct < 4; ct++) oacc[tr][ct] = 0.f;

  for (int kb = blk-1; kb <= blk+1; ++kb){
    if ((unsigned)kb > 7u) continue;
    int tokk0 = c*1025 + 1 + kb*128;

    u16x8 vlo[2], vhi[2];
#pragma unroll
    for (int i = 0; i < 2; i++){
      int gv = 4*i + w;
      const unsigned short* vp = qkv + (bT + tokk0 + 2*l)*QKV_LD + 2048 + h*64 + gv*8;
      vlo[i] = *(const u16x8*)vp;
      vhi[i] = *(const u16x8*)(vp + QKV_LD);
    }
    __syncthreads();
#pragma unroll
    for (int i = 0; i < 4; i++){
      int r = w*32 + i*8 + lr;
      int colk = (lc ^ (r & 7)) * 8;
      GLDS16(qkv + (bT + tokk0 + r)*QKV_LD + 1024 + h*64 + colk, &Ks[w*32 + i*8][0]);
    }
#pragma unroll
    for (int i = 0; i < 2; i++)
#pragma unroll
      for (int e = 0; e < 8; e++){
        unsigned pk = (unsigned)vlo[i][e] | ((unsigned)vhi[i][e] << 16);
        *(unsigned*)&Vt[(4*i + w)*8 + e][2*l] = pk;
      }
    __syncthreads();

    // joint S^T = K Q^T: kf read ONCE per (ct,ks) for both tr subtiles
    f32x4 s2[2][8];
#pragma unroll
    for (int tr = 0; tr < 2; tr++)
#pragma unroll
      for (int ct = 0; ct < 8; ct++) s2[tr][ct] = 0.f;
#pragma unroll
    for (int ct = 0; ct < 8; ct++)
#pragma unroll
      for (int ks = 0; ks < 2; ks++){
        bf16x8 kf = *(const bf16x8*)&Ks[ct*16 + li][((ks*4 + lh) ^ lsw) * 8];
        s2[0][ct] = __builtin_amdgcn_mfma_f32_16x16x32_bf16(kf, aq[0][ks], s2[0][ct], 0, 0, 0);
        s2[1][ct] = __builtin_amdgcn_mfma_f32_16x16x32_bf16(kf, aq[1][ks], s2[1][ct], 0, 0, 0);
      }

    // ks-outer PV: JIT exp+pack per tr; vf read ONCE, shared by both tr MFMAs
#pragma unroll
    for (int ks = 0; ks < 4; ks++){
      bf16x8 pa[2];
#pragma unroll
      for (int tr = 0; tr < 2; tr++){
        float q0 = __expf(s2[tr][2*ks  ][0] * 0.125f);
        float q1 = __expf(s2[tr][2*ks  ][1] * 0.125f);
        float q2 = __expf(s2[tr][2*ks  ][2] * 0.125f);
        float q3 = __expf(s2[tr][2*ks  ][3] * 0.125f);
        float q4 = __expf(s2[tr][2*ks+1][0] * 0.125f);
        float q5 = __expf(s2[tr][2*ks+1][1] * 0.125f);
        float q6 = __expf(s2[tr][2*ks+1][2] * 0.125f);
        float q7 = __expf(s2[tr][2*ks+1][3] * 0.125f);
        psum[tr] += ((q0 + q1) + (q2 + q3)) + ((q4 + q5) + (q6 + q7));
        u32x4 frv;
        frv.x = (unsigned)f2bf(q0) | ((unsigned)f2bf(q1) << 16);
        frv.y = (unsigned)f2bf(q2) | ((unsigned)f2bf(q3) << 16);
        frv.z = (unsigned)f2bf(q4) | ((unsigned)f2bf(q5) << 16);
        frv.w = (unsigned)f2bf(q6) | ((unsigned)f2bf(q7) << 16);
        pa[tr] = __builtin_bit_cast(bf16x8, frv);
      }
      int base = ks*16 + 2*lh;
#pragma unroll
      for (int ct = 0; ct < 4; ct++){
        const unsigned* vrow = (const unsigned*)&Vt[ct*16 + li][0];
        u64x2 vfv;
        vfv.x = *(const unsigned long long*)(vrow + base);
        vfv.y = *(const unsigned long long*)(vrow + base + 8);
        bf16x8 vf = __builtin_bit_cast(bf16x8, vfv);
        oacc[0][ct] = __builtin_amdgcn_mfma_f32_16x16x32_bf16(pa[0], vf, oacc[0][ct], 0, 0, 0);
        oacc[1][ct] = __builtin_amdgcn_mfma_f32_16x16x32_bf16(pa[1], vf, oacc[1][ct], 0, 0, 0);
      }
    }
  } // kb

#pragma unroll
  for (int tr = 0; tr < 2; tr++){
    psum[tr] += __shfl_xor(psum[tr], 16, 64);
    psum[tr] += __shfl_xor(psum[tr], 32, 64);
  }
  float ps[2][4];
#pragma unroll
  for (int tr = 0; tr < 2; tr++)
#pragma unroll
    for (int r = 0; r < 4; r++)
      ps[tr][r] = __shfl(psum[tr], lh*4 + r, 64);
  float gvv[4];
#pragma unroll
  for (int ct = 0; ct < 4; ct++)
    gvv[ct] = bf2f(qkv[(bT + c*1025)*QKV_LD + 2048 + h*64 + ct*16 + li]);
#pragma unroll
  for (int tr = 0; tr < 2; tr++)
#pragma unroll
    for (int ct = 0; ct < 4; ct++)
#pragma unroll
      for (int r = 0; r < 4; r++){
        int row = w*32 + tr*16 + lh*4 + r;
        float v = oacc[tr][ct][r] / ps[tr][r] + gvv[ct];
        att[(bT + tokq0 + row)*DM + h*64 + ct*16 + li] = f2bf(v);
      }
}

// ---------------- launch ----------------
extern "C" void kernel_launch(void* const* d_in, const int* in_sizes, int n_in,
                              void* d_out, int out_size, void* d_ws, size_t ws_size,
                              hipStream_t stream) {
  const float* x  = (const float*)d_in[0];
  const float* Wq = (const float*)d_in[1];
  const float* Wk = (const float*)d_in[2];
  const float* Wv = (const float*)d_in[3];
  const float* Wo = (const float*)d_in[4];
  const float* bo = (const float*)d_in[5];
  float* out = (float*)d_out;

  unsigned short* xb    = (unsigned short*)d_ws;                 // [16400][1024]
  unsigned short* wqkvt = xb    + (size_t)M_TOK * 1024;          // [3072][1024]
  unsigned short* wot   = wqkvt + (size_t)3072 * 1024;           // [1024][1024]
  unsigned short* qkv   = wot   + (size_t)1024 * 1024;           // [16400][3072]
  unsigned short* att   = qkv   + (size_t)M_TOK * QKV_LD;        // [16400][1024]

  k_prep<<<3072, 256, 0, stream>>>(x, xb, Wq, Wk, Wv, Wo, wqkvt, wot);
  k_gemm<<<dim3(129*24), 256, 0, stream>>>(xb, wqkvt, (const float*)nullptr, (void*)qkv,
                                           M_TOK, 1024, QKV_LD, 1, 24);
  k_local<<<2304, 256, 0, stream>>>(qkv, att);
  k_gemm<<<dim3(129*8), 256, 0, stream>>>(att, wot, bo, (void*)out,
                                          M_TOK, 1024, DM, 0, 8);
}

// Round 18
// 295.262 us; speedup vs baseline: 1.2047x; 1.2047x over previous
//
#include <hip/hip_runtime.h>
#include <hip/hip_bf16.h>

// ---------------- common types/helpers ----------------
typedef __bf16 bf16x8 __attribute__((ext_vector_type(8)));
typedef float  f32x4  __attribute__((ext_vector_type(4)));
typedef unsigned short u16x8 __attribute__((ext_vector_type(8)));
typedef unsigned short u16x4 __attribute__((ext_vector_type(4)));
typedef unsigned u32x4 __attribute__((ext_vector_type(4)));
typedef unsigned long long u64x2 __attribute__((ext_vector_type(2)));

#define T_TOK   8200      // C*(1+NCHUNK)
#define M_TOK   16400     // B*T
#define QKV_LD  3072
#define DM      1024

#define AS1CU const __attribute__((address_space(1))) unsigned int*
#define AS3U  __attribute__((address_space(3))) unsigned int*
#define GLDS16(g, s) __builtin_amdgcn_global_load_lds((AS1CU)(g), (AS3U)(s), 16, 0, 0)

__device__ __forceinline__ unsigned short f2bf(float f){
  __hip_bfloat16 h = __float2bfloat16(f);          // HW RNE cvt
  return *reinterpret_cast<unsigned short*>(&h);
}
__device__ __forceinline__ float bf2f(unsigned short u){
  union { unsigned u; float f; } x; x.u = ((unsigned)u) << 16;
  return x.f;
}

// ---------------- 1) fused prep: fp32->bf16 convert (blocks 0..2047) + 4x weight transpose (2048..3071) ----------------
__global__ __launch_bounds__(256) void k_prep(const float* __restrict__ x, unsigned short* __restrict__ xb,
                                              const float* __restrict__ Wq, const float* __restrict__ Wk,
                                              const float* __restrict__ Wv, const float* __restrict__ Wo,
                                              unsigned short* __restrict__ wqkvt, unsigned short* __restrict__ wot){
  __shared__ float t[64][65];
  int bid = blockIdx.x, tid = threadIdx.x;
  if (bid < 2048){
    const long n4 = (long)M_TOK * 1024 / 4;
    long i = (long)bid * 256 + tid;
    const long stride = 2048L * 256;
    for (long e = i; e < n4; e += stride){
      float4 v = ((const float4*)x)[e];
      u16x4 o; o[0]=f2bf(v.x); o[1]=f2bf(v.y); o[2]=f2bf(v.z); o[3]=f2bf(v.w);
      ((u16x4*)xb)[e] = o;
    }
    return;
  }
  int bid2 = bid - 2048;
  int z = bid2 & 3; int rest = bid2 >> 2;
  int bx = rest & 15, by = rest >> 4;
  const float* W; unsigned short* Wt;
  if      (z == 0){ W = Wq; Wt = wqkvt; }
  else if (z == 1){ W = Wk; Wt = wqkvt + (size_t)1024*1024; }
  else if (z == 2){ W = Wv; Wt = wqkvt + (size_t)2048*1024; }
  else            { W = Wo; Wt = wot; }
  int tk0 = bx * 64, tn0 = by * 64;
#pragma unroll
  for (int i = 0; i < 4; i++){
    int ch = tid + i*256; int kr = ch >> 4, n4i = (ch & 15) * 4;
    float4 v = *(const float4*)(W + (size_t)(tk0+kr)*1024 + tn0 + n4i);
    t[kr][n4i+0]=v.x; t[kr][n4i+1]=v.y; t[kr][n4i+2]=v.z; t[kr][n4i+3]=v.w;
  }
  __syncthreads();
#pragma unroll
  for (int i = 0; i < 4; i++){
    int ch = tid + i*256; int nr = ch >> 4, k4 = (ch & 15) * 4;
    u16x4 o;
#pragma unroll
    for (int e = 0; e < 4; e++) o[e] = f2bf(t[k4+e][nr]);
    *(u16x4*)(Wt + (size_t)(tn0+nr)*1024 + tk0 + k4) = o;
  }
}

// ---------------- 2) GEMM (R7 proven: n-fast tile order for A L2-reuse) ----------------
__global__ __launch_bounds__(256,2) void k_gemm(const unsigned short* __restrict__ A,
                                                const unsigned short* __restrict__ Bt,
                                                const float* __restrict__ bias,
                                                void* __restrict__ Cout,
                                                int M, int K, int ldc, int bf16out, int gn){
  __shared__ unsigned short As[128][64];
  __shared__ unsigned short Bs[128][64];
  int tid = threadIdx.x, l = tid & 63, w = tid >> 6;
  int li = l & 15, lh = l >> 4;
  int nwg = gridDim.x;
  int wg = (blockIdx.x & 7) * (nwg >> 3) + (blockIdx.x >> 3);
  int m0 = (wg / gn) * 128, n0 = (wg % gn) * 128;   // n-fast
  int wm = (w & 1) * 64, wn = (w >> 1) * 64;
  int lr = l >> 3, lc = l & 7;
  int lsw = li & 7;

  f32x4 acc[4][4];
#pragma unroll
  for (int a = 0; a < 4; a++)
#pragma unroll
    for (int b = 0; b < 4; b++) acc[a][b] = 0.f;

  for (int kt = 0; kt < K; kt += 64){
    __syncthreads();
#pragma unroll
    for (int i = 0; i < 4; i++){
      int r = w*32 + i*8 + lr;
      int colsw = (lc ^ (r & 7)) * 8;
      int rga = m0 + r; if (rga >= M) rga = M - 1;
      GLDS16(A  + (size_t)rga     *K + kt + colsw, &As[w*32 + i*8][0]);
      GLDS16(Bt + (size_t)(n0 + r)*K + kt + colsw, &Bs[w*32 + i*8][0]);
    }
    __syncthreads();
#pragma unroll
    for (int ks = 0; ks < 2; ks++){
      bf16x8 af[4], bfr[4];
#pragma unroll
      for (int mt = 0; mt < 4; mt++)
        af[mt] = *(const bf16x8*)&As[wm + mt*16 + li][((ks*4 + lh) ^ lsw) * 8];
#pragma unroll
      for (int nt = 0; nt < 4; nt++)
        bfr[nt] = *(const bf16x8*)&Bs[wn + nt*16 + li][((ks*4 + lh) ^ lsw) * 8];
#pragma unroll
      for (int mt = 0; mt < 4; mt++)
#pragma unroll
        for (int nt = 0; nt < 4; nt++)
          acc[mt][nt] = __builtin_amdgcn_mfma_f32_16x16x32_bf16(af[mt], bfr[nt], acc[mt][nt], 0, 0, 0);
    }
  }
#pragma unroll
  for (int mt = 0; mt < 4; mt++)
#pragma unroll
    for (int nt = 0; nt < 4; nt++)
#pragma unroll
      for (int r = 0; r < 4; r++){
        int row = m0 + wm + mt*16 + lh*4 + r;
        int col = n0 + wn + nt*16 + li;
        if (row < M){
          float v = acc[mt][nt][r] + (bias ? bias[col] : 0.f);
          if (bf16out) ((unsigned short*)Cout)[(size_t)row*ldc + col] = f2bf(v);
          else         ((float*)Cout)[(size_t)row*ldc + col] = v;
        }
      }
}

// ---------------- 3) attention: global-token blocks FIRST (0..255), local blocks 256..2303 ----------------
// Local path v11: joint-S (kf read once for both tr) + ks-outer PV with vf shared
// across tr — halves LDS read traffic (32->16 b128 kf, 64->32 b64 vf).
__global__ __launch_bounds__(256,3) void k_local(const unsigned short* __restrict__ qkv,
                                                 unsigned short* __restrict__ att){
  __shared__ unsigned short Ks[128][64];      // K tile, granule-swizzled | overlay for global path
  __shared__ unsigned short Vt[64][136];      // V tile transposed [d][j]

  int tid = threadIdx.x;

  if (blockIdx.x < 256){
    // ---- global-token attention (one block per (b,h,c)) ----
    float* sc   = (float*)&Ks[0][0];          // [1032]
    float* red  = sc + 1032;                  // [256]
    float* gq_s = red + 256;                  // [64]
    int gid = blockIdx.x;
    int c = gid & 7, h = (gid >> 3) & 15, b = gid >> 7;
    size_t bT = (size_t)b * T_TOK;
    size_t grow = bT + (size_t)c*1025;
    if (tid < 64) gq_s[tid] = bf2f(qkv[grow*QKV_LD + h*64 + tid]);
    __syncthreads();
    float lmax = -3e38f;
    for (int idx = tid; idx < 1032; idx += 256){
      size_t krow = (idx < 8) ? (bT + (size_t)idx*1025) : (bT + (size_t)c*1025 + 1 + (idx - 8));
      const unsigned short* kp = qkv + krow*QKV_LD + 1024 + h*64;
      float s = 0.f;
#pragma unroll
      for (int d0 = 0; d0 < 64; d0 += 8){
        u16x8 kv = *(const u16x8*)(kp + d0);
#pragma unroll
        for (int e = 0; e < 8; e++) s += gq_s[d0+e] * bf2f(kv[e]);
      }
      s *= 0.125f;
      sc[idx] = s;
      lmax = fmaxf(lmax, s);
    }
    red[tid] = lmax; __syncthreads();
    for (int st = 128; st > 0; st >>= 1){ if (tid < st) red[tid] = fmaxf(red[tid], red[tid+st]); __syncthreads(); }
    float m = red[0]; __syncthreads();
    float lsum = 0.f;
    for (int idx = tid; idx < 1032; idx += 256){
      float p = __expf(sc[idx] - m); sc[idx] = p; lsum += p;
    }
    red[tid] = lsum; __syncthreads();
    for (int st = 128; st > 0; st >>= 1){ if (tid < st) red[tid] += red[tid+st]; __syncthreads(); }
    float denom = red[0]; __syncthreads();
    int d = tid & 63, part = tid >> 6;
    float acc = 0.f;
    for (int idx = part; idx < 1032; idx += 4){
      size_t krow = (idx < 8) ? (bT + (size_t)idx*1025) : (bT + (size_t)c*1025 + 1 + (idx - 8));
      acc += sc[idx] * bf2f(qkv[krow*QKV_LD + 2048 + h*64 + d]);
    }
    red[tid] = acc; __syncthreads();
    if (tid < 64){
      float o = (red[tid] + red[tid+64] + red[tid+128] + red[tid+192]) / denom;
      att[grow*DM + h*64 + tid] = f2bf(o);
    }
    return;
  }

  // ---- local sparse 3-block attention (v11) ----
  int l = tid & 63, w = tid >> 6;
  int li = l & 15, lh = l >> 4;
  int lr = l >> 3, lc = l & 7;
  int lsw = li & 7;
  int wg0 = blockIdx.x - 256;
  int wg = (wg0 & 7) * 256 + (wg0 >> 3);    // XCD-chunked over 2048
  int blk = wg & 7, c = (wg >> 3) & 7, h = (wg >> 6) & 15, b = wg >> 10;
  size_t bT = (size_t)b * T_TOK;
  int tokq0 = c*1025 + 1 + blk*128;

  bf16x8 aq[2][2];
#pragma unroll
  for (int tr = 0; tr < 2; tr++)
#pragma unroll
    for (int ks = 0; ks < 2; ks++)
      aq[tr][ks] = *(const bf16x8*)(qkv + (bT + tokq0 + w*32 + tr*16 + li)*QKV_LD + h*64 + ks*32 + lh*8);

  float psum[2] = {0.f, 0.f};
  f32x4 oacc[2][4];
#pragma unroll
  for (int tr = 0; tr < 2; tr++)
#pragma unroll
    for (int ct = 0; ct < 4; ct++) oacc[tr][ct] = 0.f;

  for (int kb = blk-1; kb <= blk+1; ++kb){
    if ((unsigned)kb > 7u) continue;
    int tokk0 = c*1025 + 1 + kb*128;

    u16x8 vlo[2], vhi[2];
#pragma unroll
    for (int i = 0; i < 2; i++){
      int gv = 4*i + w;
      const unsigned short* vp = qkv + (bT + tokk0 + 2*l)*QKV_LD + 2048 + h*64 + gv*8;
      vlo[i] = *(const u16x8*)vp;
      vhi[i] = *(const u16x8*)(vp + QKV_LD);
    }
    __syncthreads();
#pragma unroll
    for (int i = 0; i < 4; i++){
      int r = w*32 + i*8 + lr;
      int colk = (lc ^ (r & 7)) * 8;
      GLDS16(qkv + (bT + tokk0 + r)*QKV_LD + 1024 + h*64 + colk, &Ks[w*32 + i*8][0]);
    }
#pragma unroll
    for (int i = 0; i < 2; i++)
#pragma unroll
      for (int e = 0; e < 8; e++){
        unsigned pk = (unsigned)vlo[i][e] | ((unsigned)vhi[i][e] << 16);
        *(unsigned*)&Vt[(4*i + w)*8 + e][2*l] = pk;
      }
    __syncthreads();

    // joint S^T = K Q^T: kf read ONCE per (ct,ks) for both tr subtiles
    f32x4 s2[2][8];
#pragma unroll
    for (int tr = 0; tr < 2; tr++)
#pragma unroll
      for (int ct = 0; ct < 8; ct++) s2[tr][ct] = 0.f;
#pragma unroll
    for (int ct = 0; ct < 8; ct++)
#pragma unroll
      for (int ks = 0; ks < 2; ks++){
        bf16x8 kf = *(const bf16x8*)&Ks[ct*16 + li][((ks*4 + lh) ^ lsw) * 8];
        s2[0][ct] = __builtin_amdgcn_mfma_f32_16x16x32_bf16(kf, aq[0][ks], s2[0][ct], 0, 0, 0);
        s2[1][ct] = __builtin_amdgcn_mfma_f32_16x16x32_bf16(kf, aq[1][ks], s2[1][ct], 0, 0, 0);
      }

    // ks-outer PV: JIT exp+pack per tr; vf read ONCE, shared by both tr MFMAs
#pragma unroll
    for (int ks = 0; ks < 4; ks++){
      bf16x8 pa[2];
#pragma unroll
      for (int tr = 0; tr < 2; tr++){
        float q0 = __expf(s2[tr][2*ks  ][0] * 0.125f);
        float q1 = __expf(s2[tr][2*ks  ][1] * 0.125f);
        float q2 = __expf(s2[tr][2*ks  ][2] * 0.125f);
        float q3 = __expf(s2[tr][2*ks  ][3] * 0.125f);
        float q4 = __expf(s2[tr][2*ks+1][0] * 0.125f);
        float q5 = __expf(s2[tr][2*ks+1][1] * 0.125f);
        float q6 = __expf(s2[tr][2*ks+1][2] * 0.125f);
        float q7 = __expf(s2[tr][2*ks+1][3] * 0.125f);
        psum[tr] += ((q0 + q1) + (q2 + q3)) + ((q4 + q5) + (q6 + q7));
        u32x4 frv;
        frv.x = (unsigned)f2bf(q0) | ((unsigned)f2bf(q1) << 16);
        frv.y = (unsigned)f2bf(q2) | ((unsigned)f2bf(q3) << 16);
        frv.z = (unsigned)f2bf(q4) | ((unsigned)f2bf(q5) << 16);
        frv.w = (unsigned)f2bf(q6) | ((unsigned)f2bf(q7) << 16);
        pa[tr] = __builtin_bit_cast(bf16x8, frv);
      }
      int base = ks*16 + 2*lh;
#pragma unroll
      for (int ct = 0; ct < 4; ct++){
        const unsigned* vrow = (const unsigned*)&Vt[ct*16 + li][0];
        u64x2 vfv;
        vfv.x = *(const unsigned long long*)(vrow + base);
        vfv.y = *(const unsigned long long*)(vrow + base + 8);
        bf16x8 vf = __builtin_bit_cast(bf16x8, vfv);
        oacc[0][ct] = __builtin_amdgcn_mfma_f32_16x16x32_bf16(pa[0], vf, oacc[0][ct], 0, 0, 0);
        oacc[1][ct] = __builtin_amdgcn_mfma_f32_16x16x32_bf16(pa[1], vf, oacc[1][ct], 0, 0, 0);
      }
    }
  } // kb

#pragma unroll
  for (int tr = 0; tr < 2; tr++){
    psum[tr] += __shfl_xor(psum[tr], 16, 64);
    psum[tr] += __shfl_xor(psum[tr], 32, 64);
  }
  float ps[2][4];
#pragma unroll
  for (int tr = 0; tr < 2; tr++)
#pragma unroll
    for (int r = 0; r < 4; r++)
      ps[tr][r] = __shfl(psum[tr], lh*4 + r, 64);
  float gvv[4];
#pragma unroll
  for (int ct = 0; ct < 4; ct++)
    gvv[ct] = bf2f(qkv[(bT + c*1025)*QKV_LD + 2048 + h*64 + ct*16 + li]);
#pragma unroll
  for (int tr = 0; tr < 2; tr++)
#pragma unroll
    for (int ct = 0; ct < 4; ct++)
#pragma unroll
      for (int r = 0; r < 4; r++){
        int row = w*32 + tr*16 + lh*4 + r;
        float v = oacc[tr][ct][r] / ps[tr][r] + gvv[ct];
        att[(bT + tokq0 + row)*DM + h*64 + ct*16 + li] = f2bf(v);
      }
}

// ---------------- launch ----------------
extern "C" void kernel_launch(void* const* d_in, const int* in_sizes, int n_in,
                              void* d_out, int out_size, void* d_ws, size_t ws_size,
                              hipStream_t stream) {
  const float* x  = (const float*)d_in[0];
  const float* Wq = (const float*)d_in[1];
  const float* Wk = (const float*)d_in[2];
  const float* Wv = (const float*)d_in[3];
  const float* Wo = (const float*)d_in[4];
  const float* bo = (const float*)d_in[5];
  float* out = (float*)d_out;

  unsigned short* xb    = (unsigned short*)d_ws;                 // [16400][1024]
  unsigned short* wqkvt = xb    + (size_t)M_TOK * 1024;          // [3072][1024]
  unsigned short* wot   = wqkvt + (size_t)3072 * 1024;           // [1024][1024]
  unsigned short* qkv   = wot   + (size_t)1024 * 1024;           // [16400][3072]
  unsigned short* att   = qkv   + (size_t)M_TOK * QKV_LD;        // [16400][1024]

  k_prep<<<3072, 256, 0, stream>>>(x, xb, Wq, Wk, Wv, Wo, wqkvt, wot);
  k_gemm<<<dim3(129*24), 256, 0, stream>>>(xb, wqkvt, (const float*)nullptr, (void*)qkv,
                                           M_TOK, 1024, QKV_LD, 1, 24);
  k_local<<<2304, 256, 0, stream>>>(qkv, att);
  k_gemm<<<dim3(129*8), 256, 0, stream>>>(att, wot, bo, (void*)out,
                                          M_TOK, 1024, DM, 0, 8);
}